// Round 6
// baseline (297.015 us; speedup 1.0000x reference)
//
#include <hip/hip_runtime.h>
#include <math.h>

#define N_NODES 50000
#define N_EDGES 800000
#define C 64
#define CE 32
#define NEG_SLOPE 0.2f

#define SCAN_BLOCK 256
#define SCAN_ELEMS 4                          // elems per thread
#define SCAN_TILE (SCAN_BLOCK * SCAN_ELEMS)   // 1024 per block
#define SCAN_SHIFT 10                         // log2(SCAN_TILE)
#define SCAN_NBLOCKS ((N_NODES + SCAN_TILE - 1) / SCAN_TILE)  // 49

// round-to-nearest-even fp32 -> bf16 bits
__device__ __forceinline__ unsigned bf16_rne(float f) {
    unsigned u = __float_as_uint(f);
    return (u + 0x7FFFu + ((u >> 16) & 1u)) >> 16;
}

// Kernel 1: xw = x @ W (stored bf16; only the k5 gather consumes it);
// a_i[n] = dot(watt[0:64], xw[n]); a_j[n] = dot(watt[96:160], xw[n]) from fp32 acc.
__global__ __launch_bounds__(256) void k1_xw(
    const float* __restrict__ x, const float* __restrict__ W,
    const float* __restrict__ watt,
    unsigned short* __restrict__ xwb, float* __restrict__ a_i, float* __restrict__ a_j)
{
    __shared__ float Wl[64 * 64];
    __shared__ float xs[4][64];
    int tid = threadIdx.x;
    for (int i = tid; i < 64 * 64 / 4; i += 256)
        ((float4*)Wl)[i] = ((const float4*)W)[i];
    int warp = tid >> 6, lane = tid & 63;
    int row = blockIdx.x * 4 + warp;
    if (row < N_NODES) xs[warp][lane] = x[(size_t)row * C + lane];
    __syncthreads();
    if (row >= N_NODES) return;
    float acc = 0.f;
#pragma unroll
    for (int k = 0; k < 64; k++) acc += xs[warp][k] * Wl[k * 64 + lane];
    xwb[(size_t)row * C + lane] = (unsigned short)bf16_rne(acc);
    float vi = acc * watt[lane];
    float vj = acc * watt[96 + lane];
#pragma unroll
    for (int off = 32; off; off >>= 1) {
        vi += __shfl_down(vi, off, 64);
        vj += __shfl_down(vj, off, 64);
    }
    if (lane == 0) { a_i[row] = vi; a_j[row] = vj; }
}

// Kernel 2a: pure histogram of dst (reads only the dst half of eidx)
__global__ __launch_bounds__(256) void k2a_hist(
    const int* __restrict__ eidx, unsigned* __restrict__ count)
{
    int e = blockIdx.x * 256 + threadIdx.x;
    if (e >= N_EDGES) return;
    atomicAdd(&count[eidx[N_EDGES + e]], 1u);
}

// Kernel 3a: per-block scan of 1024 counts -> exclusive-within-block base + block total
__global__ __launch_bounds__(SCAN_BLOCK) void k3a_blockscan(
    const unsigned* __restrict__ count, unsigned* __restrict__ base,
    unsigned* __restrict__ blocksum)
{
    __shared__ unsigned wsum[4];
    int tid = threadIdx.x, lane = tid & 63, warp = tid >> 6;
    int gbase = blockIdx.x * SCAN_TILE + tid * SCAN_ELEMS;
    unsigned v[SCAN_ELEMS];
    unsigned s = 0;
#pragma unroll
    for (int k = 0; k < SCAN_ELEMS; k++) {
        int i = gbase + k;
        v[k] = (i < N_NODES) ? count[i] : 0u;
        s += v[k];
    }
    unsigned inc = s;
#pragma unroll
    for (int off = 1; off < 64; off <<= 1) {
        unsigned t = __shfl_up(inc, off, 64);
        if (lane >= off) inc += t;
    }
    if (lane == 63) wsum[warp] = inc;
    __syncthreads();
    unsigned wpre = 0;
#pragma unroll
    for (int w = 0; w < 4; w++) if (w < warp) wpre += wsum[w];
    unsigned run = wpre + inc - s;
#pragma unroll
    for (int k = 0; k < SCAN_ELEMS; k++) {
        int i = gbase + k;
        if (i < N_NODES) base[i] = run;
        run += v[k];
    }
    if (tid == 255) blocksum[blockIdx.x] = wpre + inc;  // single writer: block total
}

// Kernel 3b: exclusive scan of 49 block totals (single wave)
__global__ __launch_bounds__(64) void k3b_scansums(unsigned* __restrict__ blocksum)
{
    int lane = threadIdx.x;
    unsigned v = (lane < SCAN_NBLOCKS) ? blocksum[lane] : 0u;
    unsigned inc = v;
#pragma unroll
    for (int off = 1; off < 64; off <<= 1) {
        unsigned t = __shfl_up(inc, off, 64);
        if (lane >= off) inc += t;
    }
    if (lane < SCAN_NBLOCKS) blocksum[lane] = inc - v;  // exclusive
}

// Kernel 2b (fused alpha+exp+scatter): w = exp(leakyrelu(a_i[dst] + ec + a_j[src]));
// slot claimed via cursor atomic (segment-internal order is irrelevant: any
// permutation sums identically up to fp rounding). Packed entry: src<<16 | bf16(w).
__global__ __launch_bounds__(256) void k2b_edge(
    const int* __restrict__ eidx, const float* __restrict__ edge_attr,
    const float* __restrict__ watt,
    const float* __restrict__ a_i, const float* __restrict__ a_j,
    const unsigned* __restrict__ base, const unsigned* __restrict__ blocksum,
    unsigned* __restrict__ cursor, unsigned* __restrict__ sorted)
{
    int e = blockIdx.x * 256 + threadIdx.x;
    if (e >= N_EDGES) return;
    int src = eidx[e];
    int dst = eidx[N_EDGES + e];
    const float4* ea = (const float4*)(edge_attr + (size_t)e * CE);
    float ec = 0.f;
#pragma unroll
    for (int k = 0; k < CE / 4; k++) {
        float4 v = ea[k];
        ec += v.x * watt[64 + 4 * k + 0] + v.y * watt[64 + 4 * k + 1] +
              v.z * watt[64 + 4 * k + 2] + v.w * watt[64 + 4 * k + 3];
    }
    float al = a_i[dst] + ec + a_j[src];
    al = al > 0.f ? al : NEG_SLOPE * al;
    float w = __expf(al);   // no max-subtraction: |alpha| small; normalized result identical
    unsigned pk = ((unsigned)src << 16) | bf16_rne(w);  // N_NODES=50000 < 2^16
    unsigned pos = base[dst] + blocksum[(unsigned)dst >> SCAN_SHIFT]
                 + atomicAdd(&cursor[dst], 1u);
    sorted[pos] = pk;
}

// Kernel 5: one wave per node, 8-edge-parallel bf16 gather.
// Wave = 8 groups x 8 lanes. Each group processes one edge per iteration;
// each lane loads uint4 (16 B = 8 bf16) of the source row (8 lanes x 8 ch = 64).
// Inactive lanes hold pk=0 -> w = 0.0f: contribute exactly 0 (src 0 row read, x0).
__global__ __launch_bounds__(256) void k5_gather(
    const unsigned* __restrict__ base, const unsigned* __restrict__ blocksum,
    const unsigned* __restrict__ count, const unsigned* __restrict__ sorted,
    const unsigned short* __restrict__ xwb, const float* __restrict__ bias,
    float* __restrict__ out)
{
    int warp = threadIdx.x >> 6, lane = threadIdx.x & 63;
    int node = blockIdx.x * 4 + warp;
    if (node >= N_NODES) return;
    int group = lane >> 3, sub = lane & 7;
    unsigned b = base[node] + blocksum[(unsigned)node >> SCAN_SHIFT];
    unsigned c = count[node];
    float acc[8];
#pragma unroll
    for (int i = 0; i < 8; i++) acc[i] = 0.f;
    float wpart = 0.f;
    for (unsigned chunk = 0; chunk < c; chunk += 64) {
        unsigned m = min(64u, c - chunk);
        unsigned pk = 0u;
        if (lane < m) pk = sorted[b + chunk + lane];
        wpart += __uint_as_float(pk << 16);
        unsigned iters = (m + 7) >> 3;   // wave-uniform
        for (unsigned it = 0; it < iters; it++) {
            int t = (int)(it * 8) + group;           // chunk-local edge idx, <= 63
            unsigned p = (unsigned)__shfl((int)pk, t, 64);
            float w = __uint_as_float(p << 16);
            unsigned s = p >> 16;
            uint4 v = ((const uint4*)(xwb + (size_t)s * C))[sub];
            acc[0] += w * __uint_as_float(v.x << 16);
            acc[1] += w * __uint_as_float(v.x & 0xFFFF0000u);
            acc[2] += w * __uint_as_float(v.y << 16);
            acc[3] += w * __uint_as_float(v.y & 0xFFFF0000u);
            acc[4] += w * __uint_as_float(v.z << 16);
            acc[5] += w * __uint_as_float(v.z & 0xFFFF0000u);
            acc[6] += w * __uint_as_float(v.w << 16);
            acc[7] += w * __uint_as_float(v.w & 0xFFFF0000u);
        }
    }
    // reduce acc across the 8 groups (xor 8, 16, 32)
#pragma unroll
    for (int off = 8; off < 64; off <<= 1) {
#pragma unroll
        for (int i = 0; i < 8; i++) acc[i] += __shfl_xor(acc[i], off, 64);
    }
    // full-wave reduce of wpart -> softmax denominator
#pragma unroll
    for (int off = 1; off < 64; off <<= 1)
        wpart += __shfl_xor(wpart, off, 64);
    float rden = 1.0f / (wpart + 1e-16f);
    if (group == 0) {
        float4 b4a = ((const float4*)bias)[sub * 2];
        float4 b4b = ((const float4*)bias)[sub * 2 + 1];
        float4 o1, o2;
        o1.x = acc[0] * rden + b4a.x; o1.y = acc[1] * rden + b4a.y;
        o1.z = acc[2] * rden + b4a.z; o1.w = acc[3] * rden + b4a.w;
        o2.x = acc[4] * rden + b4b.x; o2.y = acc[5] * rden + b4b.y;
        o2.z = acc[6] * rden + b4b.z; o2.w = acc[7] * rden + b4b.w;
        ((float4*)(out + (size_t)node * C))[sub * 2] = o1;
        ((float4*)(out + (size_t)node * C))[sub * 2 + 1] = o2;
    }
}

extern "C" void kernel_launch(void* const* d_in, const int* in_sizes, int n_in,
                              void* d_out, int out_size, void* d_ws, size_t ws_size,
                              hipStream_t stream) {
    const float* x         = (const float*)d_in[0];
    const int*   eidx      = (const int*)d_in[1];
    const float* edge_attr = (const float*)d_in[2];
    const float* W         = (const float*)d_in[3];
    const float* watt      = (const float*)d_in[4];
    const float* bias      = (const float*)d_in[5];
    float* out = (float*)d_out;

    char* ws = (char*)d_ws;
    size_t off = 0;
    auto alloc = [&](size_t bytes) -> void* {
        void* p = ws + off;
        off += (bytes + 255) & ~(size_t)255;
        return p;
    };
    unsigned short* xwb    = (unsigned short*)alloc((size_t)N_NODES * C * 2);  // 6.4 MB bf16
    float*    a_i      = (float*)alloc(N_NODES * 4);
    float*    a_j      = (float*)alloc(N_NODES * 4);
    unsigned* sorted   = (unsigned*)alloc((size_t)N_EDGES * 4);   // src<<16 | bf16(w)
    unsigned* basep    = (unsigned*)alloc(N_NODES * 4);
    unsigned* blocksum = (unsigned*)alloc(SCAN_NBLOCKS * 4);
    // contiguous zero-init: count + cursor
    void* zero_region = (void*)(ws + off);
    unsigned* count  = (unsigned*)alloc(N_NODES * 4);
    unsigned* cursor = (unsigned*)alloc(N_NODES * 4);

    hipMemsetAsync(zero_region, 0, (size_t)(ws + off - (char*)zero_region), stream);

    k1_xw<<<(N_NODES + 3) / 4, 256, 0, stream>>>(x, W, watt, xwb, a_i, a_j);
    k2a_hist<<<(N_EDGES + 255) / 256, 256, 0, stream>>>(eidx, count);
    k3a_blockscan<<<SCAN_NBLOCKS, SCAN_BLOCK, 0, stream>>>(count, basep, blocksum);
    k3b_scansums<<<1, 64, 0, stream>>>(blocksum);
    k2b_edge<<<(N_EDGES + 255) / 256, 256, 0, stream>>>(eidx, edge_attr, watt, a_i, a_j,
                                                        basep, blocksum, cursor, sorted);
    k5_gather<<<(N_NODES + 3) / 4, 256, 0, stream>>>(basep, blocksum, count, sorted,
                                                     xwb, bias, out);
}

// Round 7
// 257.145 us; speedup vs baseline: 1.1550x; 1.1550x over previous
//
#include <hip/hip_runtime.h>
#include <math.h>

#define N_NODES 50000
#define N_EDGES 800000
#define C 64
#define CE 32
#define NEG_SLOPE 0.2f

#define SCAN_BLOCK 256
#define SCAN_ELEMS 4                          // elems per thread
#define SCAN_TILE (SCAN_BLOCK * SCAN_ELEMS)   // 1024 per block
#define SCAN_SHIFT 10                         // log2(SCAN_TILE)
#define SCAN_NBLOCKS ((N_NODES + SCAN_TILE - 1) / SCAN_TILE)  // 49

// round-to-nearest-even fp32 -> bf16 bits
__device__ __forceinline__ unsigned bf16_rne(float f) {
    unsigned u = __float_as_uint(f);
    return (u + 0x7FFFu + ((u >> 16) & 1u)) >> 16;
}

// Kernel 1: xw = x @ W (stored bf16; only the k5 gather consumes it);
// a_i[n] = dot(watt[0:64], xw[n]); a_j[n] = dot(watt[96:160], xw[n]) from fp32 acc.
__global__ __launch_bounds__(256) void k1_xw(
    const float* __restrict__ x, const float* __restrict__ W,
    const float* __restrict__ watt,
    unsigned short* __restrict__ xwb, float* __restrict__ a_i, float* __restrict__ a_j)
{
    __shared__ float Wl[64 * 64];
    __shared__ float xs[4][64];
    int tid = threadIdx.x;
    for (int i = tid; i < 64 * 64 / 4; i += 256)
        ((float4*)Wl)[i] = ((const float4*)W)[i];
    int warp = tid >> 6, lane = tid & 63;
    int row = blockIdx.x * 4 + warp;
    if (row < N_NODES) xs[warp][lane] = x[(size_t)row * C + lane];
    __syncthreads();
    if (row >= N_NODES) return;
    float acc = 0.f;
#pragma unroll
    for (int k = 0; k < 64; k++) acc += xs[warp][k] * Wl[k * 64 + lane];
    xwb[(size_t)row * C + lane] = (unsigned short)bf16_rne(acc);
    float vi = acc * watt[lane];
    float vj = acc * watt[96 + lane];
#pragma unroll
    for (int off = 32; off; off >>= 1) {
        vi += __shfl_down(vi, off, 64);
        vj += __shfl_down(vj, off, 64);
    }
    if (lane == 0) { a_i[row] = vi; a_j[row] = vj; }
}

// Kernel 2: w = exp(leakyrelu(a_i[dst] + dot(watt[64:96], ea[e]) + a_j[src]))
// (no max-subtraction: |alpha| stays small for this data; normalized result is
// mathematically identical). Rank atomic feeds only a COALESCED write (k6 lesson:
// never put a contended atomic on a scattered store's address path).
__global__ __launch_bounds__(256) void k2_edge(
    const int* __restrict__ eidx, const float* __restrict__ edge_attr,
    const float* __restrict__ watt,
    const float* __restrict__ a_i, const float* __restrict__ a_j,
    float* __restrict__ wexp, unsigned* __restrict__ count,
    unsigned* __restrict__ erank)
{
    int e = blockIdx.x * 256 + threadIdx.x;
    if (e >= N_EDGES) return;
    int src = eidx[e];
    int dst = eidx[N_EDGES + e];
    const float4* ea = (const float4*)(edge_attr + (size_t)e * CE);
    float ec = 0.f;
#pragma unroll
    for (int k = 0; k < CE / 4; k++) {
        float4 v = ea[k];
        ec += v.x * watt[64 + 4 * k + 0] + v.y * watt[64 + 4 * k + 1] +
              v.z * watt[64 + 4 * k + 2] + v.w * watt[64 + 4 * k + 3];
    }
    float al = a_i[dst] + ec + a_j[src];
    al = al > 0.f ? al : NEG_SLOPE * al;
    wexp[e] = __expf(al);
    erank[e] = atomicAdd(&count[dst], 1u);   // rank within dst segment
}

// Kernel 3a: per-block scan of 1024 counts -> exclusive-within-block base + block total
__global__ __launch_bounds__(SCAN_BLOCK) void k3a_blockscan(
    const unsigned* __restrict__ count, unsigned* __restrict__ base,
    unsigned* __restrict__ blocksum)
{
    __shared__ unsigned wsum[4];
    int tid = threadIdx.x, lane = tid & 63, warp = tid >> 6;
    int gbase = blockIdx.x * SCAN_TILE + tid * SCAN_ELEMS;
    unsigned v[SCAN_ELEMS];
    unsigned s = 0;
#pragma unroll
    for (int k = 0; k < SCAN_ELEMS; k++) {
        int i = gbase + k;
        v[k] = (i < N_NODES) ? count[i] : 0u;
        s += v[k];
    }
    unsigned inc = s;
#pragma unroll
    for (int off = 1; off < 64; off <<= 1) {
        unsigned t = __shfl_up(inc, off, 64);
        if (lane >= off) inc += t;
    }
    if (lane == 63) wsum[warp] = inc;
    __syncthreads();
    unsigned wpre = 0;
#pragma unroll
    for (int w = 0; w < 4; w++) if (w < warp) wpre += wsum[w];
    unsigned run = wpre + inc - s;
#pragma unroll
    for (int k = 0; k < SCAN_ELEMS; k++) {
        int i = gbase + k;
        if (i < N_NODES) base[i] = run;
        run += v[k];
    }
    if (tid == 255) blocksum[blockIdx.x] = wpre + inc;  // single writer: block total
}

// Kernel 3b: exclusive scan of 49 block totals (single wave)
__global__ __launch_bounds__(64) void k3b_scansums(unsigned* __restrict__ blocksum)
{
    int lane = threadIdx.x;
    unsigned v = (lane < SCAN_NBLOCKS) ? blocksum[lane] : 0u;
    unsigned inc = v;
#pragma unroll
    for (int off = 1; off < 64; off <<= 1) {
        unsigned t = __shfl_up(inc, off, 64);
        if (lane >= off) inc += t;
    }
    if (lane < SCAN_NBLOCKS) blocksum[lane] = inc - v;  // exclusive
}

// Kernel 4: pure scatter (no atomics): sorted[base+rank] = src<<16 | bf16(w).
// All inputs coalesced; the random 4B store is fire-and-forget.
__global__ __launch_bounds__(256) void k4_scatter(
    const int* __restrict__ eidx, const float* __restrict__ wexp,
    const unsigned* __restrict__ base, const unsigned* __restrict__ blocksum,
    const unsigned* __restrict__ erank, unsigned* __restrict__ sorted)
{
    int e = blockIdx.x * 256 + threadIdx.x;
    if (e >= N_EDGES) return;
    int src = eidx[e];
    int dst = eidx[N_EDGES + e];
    unsigned pk = ((unsigned)src << 16) | bf16_rne(wexp[e]);  // N_NODES < 2^16
    unsigned pos = base[dst] + blocksum[(unsigned)dst >> SCAN_SHIFT] + erank[e];
    sorted[pos] = pk;
}

// Kernel 5: one wave per node, 8-edge-parallel bf16 gather.
// Wave = 8 groups x 8 lanes; each group one edge/iter; each lane uint4 = 8 bf16.
// Inactive lanes hold pk=0 -> w = 0.0f: contribute exactly 0.
__global__ __launch_bounds__(256) void k5_gather(
    const unsigned* __restrict__ base, const unsigned* __restrict__ blocksum,
    const unsigned* __restrict__ count, const unsigned* __restrict__ sorted,
    const unsigned short* __restrict__ xwb, const float* __restrict__ bias,
    float* __restrict__ out)
{
    int warp = threadIdx.x >> 6, lane = threadIdx.x & 63;
    int node = blockIdx.x * 4 + warp;
    if (node >= N_NODES) return;
    int group = lane >> 3, sub = lane & 7;
    unsigned b = base[node] + blocksum[(unsigned)node >> SCAN_SHIFT];
    unsigned c = count[node];
    float acc[8];
#pragma unroll
    for (int i = 0; i < 8; i++) acc[i] = 0.f;
    float wpart = 0.f;
    for (unsigned chunk = 0; chunk < c; chunk += 64) {
        unsigned m = min(64u, c - chunk);
        unsigned pk = 0u;
        if (lane < m) pk = sorted[b + chunk + lane];
        wpart += __uint_as_float(pk << 16);
        unsigned iters = (m + 7) >> 3;   // wave-uniform
        for (unsigned it = 0; it < iters; it++) {
            int t = (int)(it * 8) + group;           // chunk-local edge idx, <= 63
            unsigned p = (unsigned)__shfl((int)pk, t, 64);
            float w = __uint_as_float(p << 16);
            unsigned s = p >> 16;
            uint4 v = ((const uint4*)(xwb + (size_t)s * C))[sub];
            acc[0] += w * __uint_as_float(v.x << 16);
            acc[1] += w * __uint_as_float(v.x & 0xFFFF0000u);
            acc[2] += w * __uint_as_float(v.y << 16);
            acc[3] += w * __uint_as_float(v.y & 0xFFFF0000u);
            acc[4] += w * __uint_as_float(v.z << 16);
            acc[5] += w * __uint_as_float(v.z & 0xFFFF0000u);
            acc[6] += w * __uint_as_float(v.w << 16);
            acc[7] += w * __uint_as_float(v.w & 0xFFFF0000u);
        }
    }
    // reduce acc across the 8 groups (xor 8, 16, 32)
#pragma unroll
    for (int off = 8; off < 64; off <<= 1) {
#pragma unroll
        for (int i = 0; i < 8; i++) acc[i] += __shfl_xor(acc[i], off, 64);
    }
    // full-wave reduce of wpart -> softmax denominator
#pragma unroll
    for (int off = 1; off < 64; off <<= 1)
        wpart += __shfl_xor(wpart, off, 64);
    float rden = 1.0f / (wpart + 1e-16f);
    if (group == 0) {
        float4 b4a = ((const float4*)bias)[sub * 2];
        float4 b4b = ((const float4*)bias)[sub * 2 + 1];
        float4 o1, o2;
        o1.x = acc[0] * rden + b4a.x; o1.y = acc[1] * rden + b4a.y;
        o1.z = acc[2] * rden + b4a.z; o1.w = acc[3] * rden + b4a.w;
        o2.x = acc[4] * rden + b4b.x; o2.y = acc[5] * rden + b4b.y;
        o2.z = acc[6] * rden + b4b.z; o2.w = acc[7] * rden + b4b.w;
        ((float4*)(out + (size_t)node * C))[sub * 2] = o1;
        ((float4*)(out + (size_t)node * C))[sub * 2 + 1] = o2;
    }
}

extern "C" void kernel_launch(void* const* d_in, const int* in_sizes, int n_in,
                              void* d_out, int out_size, void* d_ws, size_t ws_size,
                              hipStream_t stream) {
    const float* x         = (const float*)d_in[0];
    const int*   eidx      = (const int*)d_in[1];
    const float* edge_attr = (const float*)d_in[2];
    const float* W         = (const float*)d_in[3];
    const float* watt      = (const float*)d_in[4];
    const float* bias      = (const float*)d_in[5];
    float* out = (float*)d_out;

    char* ws = (char*)d_ws;
    size_t off = 0;
    auto alloc = [&](size_t bytes) -> void* {
        void* p = ws + off;
        off += (bytes + 255) & ~(size_t)255;
        return p;
    };
    unsigned short* xwb = (unsigned short*)alloc((size_t)N_NODES * C * 2);  // 6.4 MB bf16
    float*    a_i      = (float*)alloc(N_NODES * 4);
    float*    a_j      = (float*)alloc(N_NODES * 4);
    float*    wexp     = (float*)alloc(N_EDGES * 4);
    unsigned* erank    = (unsigned*)alloc(N_EDGES * 4);
    unsigned* sorted   = (unsigned*)alloc((size_t)N_EDGES * 4);   // src<<16 | bf16(w)
    unsigned* basep    = (unsigned*)alloc(N_NODES * 4);
    unsigned* blocksum = (unsigned*)alloc(SCAN_NBLOCKS * 4);
    unsigned* count    = (unsigned*)alloc(N_NODES * 4);

    hipMemsetAsync(count, 0, (size_t)N_NODES * 4, stream);

    k1_xw<<<(N_NODES + 3) / 4, 256, 0, stream>>>(x, W, watt, xwb, a_i, a_j);
    k2_edge<<<(N_EDGES + 255) / 256, 256, 0, stream>>>(eidx, edge_attr, watt, a_i, a_j,
                                                       wexp, count, erank);
    k3a_blockscan<<<SCAN_NBLOCKS, SCAN_BLOCK, 0, stream>>>(count, basep, blocksum);
    k3b_scansums<<<1, 64, 0, stream>>>(blocksum);
    k4_scatter<<<(N_EDGES + 255) / 256, 256, 0, stream>>>(eidx, wexp, basep, blocksum,
                                                          erank, sorted);
    k5_gather<<<(N_NODES + 3) / 4, 256, 0, stream>>>(basep, blocksum, count, sorted,
                                                     xwb, bias, out);
}